// Round 2
// baseline (362.111 us; speedup 1.0000x reference)
//
#include <hip/hip_runtime.h>
#include <hip/hip_bf16.h>

typedef __bf16 bf16x8 __attribute__((ext_vector_type(8)));
typedef __bf16 bf16x4 __attribute__((ext_vector_type(4)));
typedef float  f32x4  __attribute__((ext_vector_type(4)));

#define NTOK 16384
#define DDIM 1024
#define HDIM 1024
#define NEXP 8
#define CNT_STRIDE 16   // ints between counters -> separate cachelines

// workspace layout (bytes)
#define XB_OFF   0u          // bf16 x        [NTOK][DDIM]   33,554,432
#define WT_OFF   33554432u   // bf16 W^T      [E][H][D]      16,777,216
#define IDX_OFF  50331648u   // int  idx      [E][NTOK]         524,288
#define PRB_OFF  50855936u   // f32  prob     [E][NTOK]         524,288
#define CNT_OFF  51380224u   // int  counts   [8*16] padded      512
#define ENT_OFF  51380736u   // f32  entropy acc                 4

typedef __attribute__((address_space(1))) void gvoid_t;
typedef __attribute__((address_space(3))) void lvoid_t;

__device__ __forceinline__ void cp16(void* lds, const void* g) {
  // async global->LDS, 16B per lane; LDS dest = wave-uniform base + lane*16
  __builtin_amdgcn_global_load_lds((gvoid_t*)g, (lvoid_t*)lds, 16, 0, 0);
}

// ---------------- fused prep: blocks [0,2048) transpose W, [2048,3072) gate ------
// transpose: expert_w [E][D][H] f32 -> W^T [E][H][D] bf16
// gate: logits/softmax/entropy/top2, routing lists, x->bf16, out = p1*b1+p2*b2
union SmemU {
  float tile[64][68];             // transpose branch (17.4 KB)
  struct {
    float gwT[8 * 1032];          // gate_w^T, padded row stride (33.0 KB)
    int   lidx[8 * 32];
    float lprob[8 * 32];
    int   lcnt[8];
    int   gbase[8];
    float went[4];
  } g;
};

__global__ __launch_bounds__(256) void prep_kernel(
    const float* __restrict__ x, const float* __restrict__ gw,
    const float* __restrict__ gb, const float* __restrict__ ew,
    const float* __restrict__ eb, __bf16* __restrict__ xb,
    __bf16* __restrict__ wT, int* __restrict__ idx_g,
    float* __restrict__ prob_g, int* __restrict__ cnt_g,
    float* __restrict__ ent_g, float* __restrict__ out) {
  __shared__ SmemU sm;
  const int tid = threadIdx.x;

  if (blockIdx.x < 2048) {
    // ---- transpose branch ----
    const int b  = blockIdx.x;
    const int e  = b >> 8;
    const int d0 = ((b >> 4) & 15) * 64;
    const int h0 = (b & 15) * 64;
    const float* base = ew + ((size_t)e * DDIM + d0) * HDIM + h0;
#pragma unroll
    for (int it = 0; it < 4; ++it) {
      int dl = it * 16 + (tid >> 4);
      int hl = (tid & 15) * 4;
      float4 v = *(const float4*)(base + (size_t)dl * HDIM + hl);
      sm.tile[dl][hl]     = v.x;
      sm.tile[dl][hl + 1] = v.y;
      sm.tile[dl][hl + 2] = v.z;
      sm.tile[dl][hl + 3] = v.w;
    }
    __syncthreads();
    __bf16* obase = wT + ((size_t)e * HDIM + h0) * DDIM + d0;
#pragma unroll
    for (int it = 0; it < 4; ++it) {
      int hl = it * 16 + (tid >> 4);
      int dl = (tid & 15) * 4;
      bf16x4 bv;
      bv[0] = (__bf16)sm.tile[dl][hl];
      bv[1] = (__bf16)sm.tile[dl + 1][hl];
      bv[2] = (__bf16)sm.tile[dl + 2][hl];
      bv[3] = (__bf16)sm.tile[dl + 3][hl];
      *(bf16x4*)(obase + (size_t)hl * DDIM + dl) = bv;
    }
    return;
  }

  // ---- gate branch: 1024 blocks, 16 tokens each (wave-per-token, 4 t-iters) ----
  const int gbid = blockIdx.x - 2048;
  const int w = tid >> 6, lane = tid & 63;
  if (tid < 8) sm.g.lcnt[tid] = 0;
#pragma unroll
  for (int i = 0; i < 32; ++i) {  // gate_w [D][8] -> gwT [8][1032] in LDS
    int lin = i * 256 + tid;
    sm.g.gwT[(lin & 7) * 1032 + (lin >> 3)] = gw[lin];
  }
  float gbr[8];
#pragma unroll
  for (int e = 0; e < 8; ++e) gbr[e] = gb[e];
  __syncthreads();

  float entacc = 0.f;
  for (int t = 0; t < 4; ++t) {
    const int n = gbid * 16 + w * 4 + t;
    float acc[8] = {0.f, 0.f, 0.f, 0.f, 0.f, 0.f, 0.f, 0.f};
#pragma unroll
    for (int j = 0; j < 4; ++j) {
      float4 v = *(const float4*)(x + (size_t)n * DDIM + j * 256 + lane * 4);
      bf16x4 bv;
      bv[0] = (__bf16)v.x; bv[1] = (__bf16)v.y;
      bv[2] = (__bf16)v.z; bv[3] = (__bf16)v.w;
      *(bf16x4*)(xb + (size_t)n * DDIM + j * 256 + lane * 4) = bv;
#pragma unroll
      for (int e = 0; e < 8; ++e) {
        float4 g = *(const float4*)&sm.g.gwT[e * 1032 + j * 256 + lane * 4];
        acc[e] += v.x * g.x + v.y * g.y + v.z * g.z + v.w * g.w;
      }
    }
#pragma unroll
    for (int e = 0; e < 8; ++e) {
      float s = acc[e];
#pragma unroll
      for (int off = 1; off < 64; off <<= 1) s += __shfl_xor(s, off);
      acc[e] = s;  // all lanes now hold the full logit
    }
    // redundant per-lane softmax/top-2 (no divergence, no broadcast needed)
    float p[8];
    float mx = -1e30f;
#pragma unroll
    for (int e = 0; e < 8; ++e) { p[e] = acc[e] + gbr[e]; mx = fmaxf(mx, p[e]); }
    float s = 0.f;
#pragma unroll
    for (int e = 0; e < 8; ++e) { p[e] = expf(p[e] - mx); s += p[e]; }
    float inv = 1.0f / s;
    float ent = 0.f;
#pragma unroll
    for (int e = 0; e < 8; ++e) { p[e] *= inv; ent -= p[e] * logf(p[e] + 1e-10f); }
    entacc += ent;
    int e1 = 0; float p1 = p[0];
#pragma unroll
    for (int e = 1; e < 8; ++e) if (p[e] > p1) { p1 = p[e]; e1 = e; }
    int e2 = (e1 == 0) ? 1 : 0; float p2 = p[e2];
#pragma unroll
    for (int e = 0; e < 8; ++e) if (e != e1 && p[e] > p2) { p2 = p[e]; e2 = e; }
    if (lane == 0) {
      int j = atomicAdd(&sm.g.lcnt[e1], 1);
      sm.g.lidx[e1 * 32 + j] = n; sm.g.lprob[e1 * 32 + j] = p1;
      j = atomicAdd(&sm.g.lcnt[e2], 1);
      sm.g.lidx[e2 * 32 + j] = n; sm.g.lprob[e2 * 32 + j] = p2;
    }
    // out[n] = p1*b[e1] + p2*b[e2]  (fused init_out)
    const float4* b1 = (const float4*)(eb + (size_t)e1 * HDIM);
    const float4* b2 = (const float4*)(eb + (size_t)e2 * HDIM);
    float4* orow = (float4*)(out + (size_t)n * HDIM);
#pragma unroll
    for (int j = 0; j < 4; ++j) {
      int hi = j * 64 + lane;
      float4 v1 = b1[hi], v2 = b2[hi], r;
      r.x = p1 * v1.x + p2 * v2.x;
      r.y = p1 * v1.y + p2 * v2.y;
      r.z = p1 * v1.z + p2 * v2.z;
      r.w = p1 * v1.w + p2 * v2.w;
      orow[hi] = r;
    }
  }
  if (lane == 0) sm.g.went[w] = entacc;
  __syncthreads();
  if (tid < 8) sm.g.gbase[tid] = atomicAdd(&cnt_g[tid * CNT_STRIDE], sm.g.lcnt[tid]);
  if (tid == 0)
    atomicAdd(ent_g, sm.g.went[0] + sm.g.went[1] + sm.g.went[2] + sm.g.went[3]);
  __syncthreads();
#pragma unroll
  for (int e = 0; e < 8; ++e) {
    for (int j = tid; j < sm.g.lcnt[e]; j += 256) {
      idx_g[e * NTOK + sm.g.gbase[e] + j]  = sm.g.lidx[e * 32 + j];
      prob_g[e * NTOK + sm.g.gbase[e] + j] = sm.g.lprob[e * 32 + j];
    }
  }
}

// ---------------- grouped gathered GEMM, XOR-swizzled LDS, scatter-add epilogue ---
__global__ __launch_bounds__(256) void moe_gemm(
    const __bf16* __restrict__ xb, const __bf16* __restrict__ wT,
    const int* __restrict__ idx_g, const float* __restrict__ prob_g,
    const int* __restrict__ cnt_g, float* __restrict__ out) {
  const int e = blockIdx.z, gy = blockIdx.y, gx = blockIdx.x;
  const int cnt = cnt_g[e * CNT_STRIDE];
  if (cnt == 0 || gy * 128 >= cnt) return;

  __shared__ __bf16 Ash[128 * 64];
  __shared__ __bf16 Bsh[128 * 64];
  __shared__ int    tok_s[128];
  __shared__ float  p_s[128];

  const int tid = threadIdx.x, w = tid >> 6, lane = tid & 63;
  if (tid < 128) {
    int gm  = gy * 128 + tid;
    int src = (gm < cnt) ? gm : (cnt - 1);
    tok_s[tid] = idx_g[e * NTOK + src];
    p_s[tid]   = (gm < cnt) ? prob_g[e * NTOK + src] : 0.0f;
  }
  __syncthreads();

  f32x4 acc[4][4];
  const f32x4 zero = {0.f, 0.f, 0.f, 0.f};
#pragma unroll
  for (int mi = 0; mi < 4; ++mi)
#pragma unroll
    for (int ni = 0; ni < 4; ++ni) acc[mi][ni] = zero;

  const __bf16* wbase = wT + (size_t)e * HDIM * DDIM + (size_t)(gx * 128) * DDIM;
  const int wm = (w >> 1) * 64, wn = (w & 1) * 64;
  const int tq = lane >> 4, tr = lane & 15, tr7 = tr & 7;
  const int rsub = lane >> 3;
  // staging swizzle: LDS chunk (lane&7) of row r holds global chunk (lane&7)^(r&7)
  const int csw = ((lane & 7) ^ (rsub & 7)) * 8;  // bf16 elements

  for (int kk = 0; kk < 16; ++kk) {
    const int k0 = kk * 64;
#pragma unroll
    for (int it = 0; it < 4; ++it) {  // stage A: 128 rows x 64 k (gathered)
      int rb = it * 32 + w * 8;
      int r  = rb + rsub;
      cp16((char*)Ash + rb * 128,
           xb + (size_t)tok_s[r] * DDIM + k0 + csw);
    }
#pragma unroll
    for (int it = 0; it < 4; ++it) {  // stage B: 128 n-rows x 64 k from W^T
      int rb = it * 32 + w * 8;
      int r  = rb + rsub;
      cp16((char*)Bsh + rb * 128,
           wbase + (size_t)r * DDIM + k0 + csw);
    }
    __syncthreads();
#pragma unroll
    for (int h = 0; h < 2; ++h) {
      bf16x8 a[4], b[4];
#pragma unroll
      for (int mi = 0; mi < 4; ++mi) {
        int row = wm + mi * 16 + tr;
        a[mi] = *(const bf16x8*)((const char*)Ash + row * 128 +
                                 ((((h << 2) | tq) ^ tr7) << 4));
      }
#pragma unroll
      for (int ni = 0; ni < 4; ++ni) {
        int row = wn + ni * 16 + tr;
        b[ni] = *(const bf16x8*)((const char*)Bsh + row * 128 +
                                 ((((h << 2) | tq) ^ tr7) << 4));
      }
#pragma unroll
      for (int mi = 0; mi < 4; ++mi)
#pragma unroll
        for (int ni = 0; ni < 4; ++ni)
          acc[mi][ni] = __builtin_amdgcn_mfma_f32_16x16x32_bf16(a[mi], b[ni], acc[mi][ni], 0, 0, 0);
    }
    __syncthreads();
  }

  // epilogue: C/D layout col=lane&15, row=quad*4+reg; scale by prob, scatter-add
#pragma unroll
  for (int mi = 0; mi < 4; ++mi) {
#pragma unroll
    for (int r = 0; r < 4; ++r) {
      int lr = wm + mi * 16 + tq * 4 + r;
      int gm = gy * 128 + lr;
      if (gm < cnt) {
        int   tok = tok_s[lr];
        float p   = p_s[lr];
        float* orow = out + (size_t)tok * HDIM + gx * 128 + wn + tr;
#pragma unroll
        for (int ni = 0; ni < 4; ++ni)
          atomicAdd(orow + ni * 16, p * acc[mi][ni][r]);
      }
    }
  }
}

// ---------------- scalar loss ----------------
__global__ void finalize(const float* __restrict__ ent_g, const int* __restrict__ cnt_g,
                         float* __restrict__ loss_out) {
  if (threadIdx.x == 0) {
    float ent = ent_g[0] / (float)NTOK;
    float pen = 0.f;
    for (int e = 0; e < 8; ++e) {
      float r = (float)cnt_g[e * CNT_STRIDE] / (float)NTOK - 0.3f;
      if (r > 0.f) pen += r;
    }
    loss_out[0] = 0.1f * ent + pen;
  }
}

extern "C" void kernel_launch(void* const* d_in, const int* in_sizes, int n_in,
                              void* d_out, int out_size, void* d_ws, size_t ws_size,
                              hipStream_t stream) {
  const float* x  = (const float*)d_in[0];
  const float* gw = (const float*)d_in[1];
  const float* gb = (const float*)d_in[2];
  const float* ew = (const float*)d_in[3];
  const float* eb = (const float*)d_in[4];
  float* out = (float*)d_out;
  char*  ws  = (char*)d_ws;

  __bf16* xb     = (__bf16*)(ws + XB_OFF);
  __bf16* wT     = (__bf16*)(ws + WT_OFF);
  int*    idx_g  = (int*)(ws + IDX_OFF);
  float*  prob_g = (float*)(ws + PRB_OFF);
  int*    cnt_g  = (int*)(ws + CNT_OFF);
  float*  ent_g  = (float*)(ws + ENT_OFF);

  hipMemsetAsync(ws + CNT_OFF, 0, 1024, stream);
  prep_kernel<<<dim3(3072), 256, 0, stream>>>(x, gw, gb, ew, eb, xb, wT,
                                              idx_g, prob_g, cnt_g, ent_g, out);
  moe_gemm<<<dim3(8, 128, 8), 256, 0, stream>>>(xb, wT, idx_g, prob_g, cnt_g, out);
  finalize<<<1, 64, 0, stream>>>(ent_g, cnt_g, out + (size_t)NTOK * HDIM);
}

// Round 3
// 327.876 us; speedup vs baseline: 1.1044x; 1.1044x over previous
//
#include <hip/hip_runtime.h>
#include <hip/hip_bf16.h>

typedef __bf16 bf16x8 __attribute__((ext_vector_type(8)));
typedef __bf16 bf16x4 __attribute__((ext_vector_type(4)));
typedef float  f32x4  __attribute__((ext_vector_type(4)));

#define NTOK 16384
#define DDIM 1024
#define HDIM 1024
#define CNT_STRIDE 16   // ints between counters -> separate cachelines

// workspace layout (bytes)
#define XB_OFF   0u          // bf16 x        [NTOK][DDIM]     33,554,432
#define WT_OFF   33554432u   // bf16 W^T      [E][H][D]        16,777,216
#define IDXP_OFF 50331648u   // int   idx_packed [NTOK]            65,536
#define PPP_OFF  50397184u   // f32x2 pp_packed  [NTOK]           131,072
#define TPID_OFF 50528256u   // int   tt_pid [NTOK]                65,536
#define TPP_OFF  50593792u   // f32x2 tt_pp  [NTOK]               131,072
#define CNT_OFF  50724864u   // int cnt[64*16]                      4,096
#define CUR_OFF  50728960u   // int cur[64*16]                      4,096
#define BASE_OFF 50733056u   // int base[64]                          256
#define TILT_OFF 50733312u   // int4 tile_table[192]                3,072
#define NT_OFF   50736384u   // int n_tiles
#define ENT_OFF  50736388u   // f32 entropy acc
#define ZERO_LEN 11536u      // memset from CNT_OFF

typedef __attribute__((address_space(1))) void gvoid_t;
typedef __attribute__((address_space(3))) void lvoid_t;

__device__ __forceinline__ void cp16(void* lds, const void* g) {
  __builtin_amdgcn_global_load_lds((gvoid_t*)g, (lvoid_t*)lds, 16, 0, 0);
}

// ---------------- expert_w [E][D][H] f32 -> W^T [E][H][D] bf16 ----------------
__global__ __launch_bounds__(256) void transpose_w(const float* __restrict__ w,
                                                   __bf16* __restrict__ wT) {
  const int b  = blockIdx.x;
  const int e  = b >> 8;
  const int d0 = ((b >> 4) & 15) * 64;
  const int h0 = (b & 15) * 64;
  __shared__ float tile[64][68];
  const int t = threadIdx.x;
  const float* base = w + ((size_t)e * DDIM + d0) * HDIM + h0;
#pragma unroll
  for (int it = 0; it < 4; ++it) {
    int dl = it * 16 + (t >> 4);
    int hl = (t & 15) * 4;
    float4 v = *(const float4*)(base + (size_t)dl * HDIM + hl);
    tile[dl][hl]     = v.x;
    tile[dl][hl + 1] = v.y;
    tile[dl][hl + 2] = v.z;
    tile[dl][hl + 3] = v.w;
  }
  __syncthreads();
  __bf16* obase = wT + ((size_t)e * HDIM + h0) * DDIM + d0;
#pragma unroll
  for (int it = 0; it < 4; ++it) {
    int hl = it * 16 + (t >> 4);
    int dl = (t & 15) * 4;
    bf16x4 bv;
    bv[0] = (__bf16)tile[dl][hl];
    bv[1] = (__bf16)tile[dl + 1][hl];
    bv[2] = (__bf16)tile[dl + 2][hl];
    bv[3] = (__bf16)tile[dl + 3][hl];
    *(bf16x4*)(obase + (size_t)hl * DDIM + dl) = bv;
  }
}

// ---------------- gate: logits/softmax/entropy/top2 -> pid+probs, x->bf16 ------
__global__ __launch_bounds__(256) void gate_kernel(
    const float* __restrict__ x, const float* __restrict__ gw,
    const float* __restrict__ gb, __bf16* __restrict__ xb,
    int* __restrict__ tt_pid, float2* __restrict__ tt_pp,
    int* __restrict__ cnt_g, float* __restrict__ ent_g) {
  __shared__ float gwT[8 * 1024];
  __shared__ int   lcnt[64];
  __shared__ float went[4];
  const int tid = threadIdx.x, w = tid >> 6, lane = tid & 63;
  for (int i = tid; i < 64; i += 256) lcnt[i] = 0;
#pragma unroll
  for (int i = 0; i < 32; ++i) {  // gate_w [D][8] -> gwT [8][1024]
    int lin = i * 256 + tid;
    gwT[(lin & 7) * 1024 + (lin >> 3)] = gw[lin];
  }
  __syncthreads();
  // cache gate_w fragments in registers: invariant across tokens
  float4 gr[4][8];
#pragma unroll
  for (int j = 0; j < 4; ++j)
#pragma unroll
    for (int e = 0; e < 8; ++e)
      gr[j][e] = *(const float4*)&gwT[e * 1024 + j * 256 + lane * 4];
  float gbr[8];
#pragma unroll
  for (int e = 0; e < 8; ++e) gbr[e] = gb[e];

  float entacc = 0.f;
  for (int t = 0; t < 4; ++t) {
    const int n = blockIdx.x * 16 + w * 4 + t;
    float acc[8] = {0.f, 0.f, 0.f, 0.f, 0.f, 0.f, 0.f, 0.f};
#pragma unroll
    for (int j = 0; j < 4; ++j) {
      float4 v = *(const float4*)(x + (size_t)n * DDIM + j * 256 + lane * 4);
      bf16x4 bv;
      bv[0] = (__bf16)v.x; bv[1] = (__bf16)v.y;
      bv[2] = (__bf16)v.z; bv[3] = (__bf16)v.w;
      *(bf16x4*)(xb + (size_t)n * DDIM + j * 256 + lane * 4) = bv;
#pragma unroll
      for (int e = 0; e < 8; ++e) {
        float4 g = gr[j][e];
        acc[e] += v.x * g.x + v.y * g.y + v.z * g.z + v.w * g.w;
      }
    }
#pragma unroll
    for (int e = 0; e < 8; ++e) {
      float s = acc[e];
#pragma unroll
      for (int off = 1; off < 64; off <<= 1) s += __shfl_xor(s, off);
      acc[e] = s;
    }
    float p[8];
    float mx = -1e30f;
#pragma unroll
    for (int e = 0; e < 8; ++e) { p[e] = acc[e] + gbr[e]; mx = fmaxf(mx, p[e]); }
    float s = 0.f;
#pragma unroll
    for (int e = 0; e < 8; ++e) { p[e] = expf(p[e] - mx); s += p[e]; }
    float inv = 1.0f / s;
    float ent = 0.f;
#pragma unroll
    for (int e = 0; e < 8; ++e) { p[e] *= inv; ent -= p[e] * logf(p[e] + 1e-10f); }
    entacc += ent;
    int e1 = 0; float p1 = p[0];
#pragma unroll
    for (int e = 1; e < 8; ++e) if (p[e] > p1) { p1 = p[e]; e1 = e; }
    int e2 = (e1 == 0) ? 1 : 0; float p2 = p[e2];
#pragma unroll
    for (int e = 0; e < 8; ++e) if (e != e1 && p[e] > p2) { p2 = p[e]; e2 = e; }
    // ordered pair (lo<hi) with matching probs
    int   elo = (e1 < e2) ? e1 : e2;
    int   ehi = (e1 < e2) ? e2 : e1;
    float plo = (e1 < e2) ? p1 : p2;
    float phi = (e1 < e2) ? p2 : p1;
    int pid = elo * 8 + ehi;
    if (lane == 0) {
      tt_pid[n] = pid;
      tt_pp[n]  = make_float2(plo, phi);
      atomicAdd(&lcnt[pid], 1);
    }
  }
  if (lane == 0) went[w] = entacc;
  __syncthreads();
  if (tid < 64 && lcnt[tid]) atomicAdd(&cnt_g[tid * CNT_STRIDE], lcnt[tid]);
  if (tid == 0)
    atomicAdd(ent_g, went[0] + went[1] + went[2] + went[3]);
}

// ---------------- scan: bases, tile table, fused loss ----------------
__global__ void scan_kernel(const int* __restrict__ cnt_g, int* __restrict__ base_g,
                            int4* __restrict__ tilt, int* __restrict__ nt_g,
                            const float* __restrict__ ent_g, float* __restrict__ loss_out) {
  if (threadIdx.x == 0) {
    int b = 0, t = 0;
    int ecnt[8] = {0, 0, 0, 0, 0, 0, 0, 0};
    for (int pid = 0; pid < 64; ++pid) {
      int c = cnt_g[pid * CNT_STRIDE];
      base_g[pid] = b;
      if (c > 0) {
        ecnt[pid >> 3] += c;
        ecnt[pid & 7]  += c;
        for (int r = 0; r < c; r += 128) tilt[t++] = make_int4(pid, r, c, b);
        b += c;
      }
    }
    *nt_g = t;
    float pen = 0.f;
    for (int e = 0; e < 8; ++e) {
      float r = (float)ecnt[e] / (float)NTOK - 0.3f;
      if (r > 0.f) pen += r;
    }
    loss_out[0] = 0.1f * (ent_g[0] / (float)NTOK) + pen;
  }
}

// ---------------- scatter: pack tokens into per-group lists ----------------
__global__ __launch_bounds__(256) void scatter_kernel(
    const int* __restrict__ tt_pid, const float2* __restrict__ tt_pp,
    const int* __restrict__ base_g, int* __restrict__ cur_g,
    int* __restrict__ idx_p, float2* __restrict__ pp_p) {
  __shared__ int lcnt[64], lbase[64];
  const int tid = threadIdx.x;
  if (tid < 64) lcnt[tid] = 0;
  __syncthreads();
  const int n = blockIdx.x * 256 + tid;
  const int pid = tt_pid[n];
  int lofs = atomicAdd(&lcnt[pid], 1);
  __syncthreads();
  if (tid < 64 && lcnt[tid]) lbase[tid] = atomicAdd(&cur_g[tid * CNT_STRIDE], lcnt[tid]);
  __syncthreads();
  int dst = base_g[pid] + lbase[pid] + lofs;
  idx_p[dst] = n;
  pp_p[dst]  = tt_pp[n];
}

// ---------------- pair-grouped dual-expert GEMM, no atomics ----------------
__global__ __launch_bounds__(256) void moe_gemm(
    const __bf16* __restrict__ xb, const __bf16* __restrict__ wT,
    const float* __restrict__ eb, const int* __restrict__ idx_p,
    const float2* __restrict__ pp_p, const int4* __restrict__ tilt,
    const int* __restrict__ nt_g, float* __restrict__ out) {
  const int gy = blockIdx.y;
  if (gy >= *nt_g) return;
  const int4 te = tilt[gy];
  const int pid = te.x, row0 = te.y, cntp = te.z, gbase = te.w;
  const int elo = pid >> 3, ehi = pid & 7;
  const int gx = blockIdx.x;

  __shared__ __bf16 Ash[128 * 64];
  __shared__ __bf16 BloS[128 * 64];
  __shared__ __bf16 BhiS[128 * 64];
  __shared__ int    tok_s[128];
  __shared__ float2 pp_s[128];

  const int tid = threadIdx.x, w = tid >> 6, lane = tid & 63;
  if (tid < 128) {
    int s = row0 + tid;
    int g = gbase + ((s < cntp) ? s : (cntp - 1));
    tok_s[tid] = idx_p[g];
    pp_s[tid]  = pp_p[g];
  }
  __syncthreads();

  f32x4 accL[4][4], accH[4][4];
  const f32x4 zero = {0.f, 0.f, 0.f, 0.f};
#pragma unroll
  for (int mi = 0; mi < 4; ++mi)
#pragma unroll
    for (int ni = 0; ni < 4; ++ni) { accL[mi][ni] = zero; accH[mi][ni] = zero; }

  const int wm = (w >> 1) * 64, wn = (w & 1) * 64;
  const int tq = lane >> 4, tr = lane & 15, tr7 = tr & 7;
  const int rsub = lane >> 3;
  const int csw = ((lane & 7) ^ rsub) * 8;  // bf16 elems; staging XOR swizzle

  const __bf16* wlo = wT + (size_t)elo * HDIM * DDIM + (size_t)(gx * 128) * DDIM;
  const __bf16* whi = wT + (size_t)ehi * HDIM * DDIM + (size_t)(gx * 128) * DDIM;
  const __bf16* aptr[4];
  const __bf16* lptr[4];
  const __bf16* hptr[4];
#pragma unroll
  for (int it = 0; it < 4; ++it) {
    int r = it * 32 + w * 8 + rsub;
    aptr[it] = xb + (size_t)tok_s[r] * DDIM + csw;
    lptr[it] = wlo + (size_t)r * DDIM + csw;
    hptr[it] = whi + (size_t)r * DDIM + csw;
  }

  for (int kk = 0; kk < 16; ++kk) {
#pragma unroll
    for (int it = 0; it < 4; ++it) {
      const int rb = it * 32 + w * 8;
      cp16((char*)Ash  + rb * 128, aptr[it]); aptr[it] += 64;
      cp16((char*)BloS + rb * 128, lptr[it]); lptr[it] += 64;
      cp16((char*)BhiS + rb * 128, hptr[it]); hptr[it] += 64;
    }
    __syncthreads();
#pragma unroll
    for (int h = 0; h < 2; ++h) {
      const int co = (h << 2) | tq;
      bf16x8 a[4], bl[4], bh[4];
#pragma unroll
      for (int mi = 0; mi < 4; ++mi)
        a[mi] = *(const bf16x8*)((const char*)Ash + (wm + mi * 16 + tr) * 128 +
                                 ((co ^ tr7) << 4));
#pragma unroll
      for (int ni = 0; ni < 4; ++ni) {
        bl[ni] = *(const bf16x8*)((const char*)BloS + (wn + ni * 16 + tr) * 128 +
                                  ((co ^ tr7) << 4));
        bh[ni] = *(const bf16x8*)((const char*)BhiS + (wn + ni * 16 + tr) * 128 +
                                  ((co ^ tr7) << 4));
      }
#pragma unroll
      for (int mi = 0; mi < 4; ++mi)
#pragma unroll
        for (int ni = 0; ni < 4; ++ni) {
          accL[mi][ni] = __builtin_amdgcn_mfma_f32_16x16x32_bf16(a[mi], bl[ni], accL[mi][ni], 0, 0, 0);
          accH[mi][ni] = __builtin_amdgcn_mfma_f32_16x16x32_bf16(a[mi], bh[ni], accH[mi][ni], 0, 0, 0);
        }
    }
    __syncthreads();
  }

  // epilogue: out = plo*(accL + b_lo) + phi*(accH + b_hi), single plain store
  float blov[4], bhiv[4];
#pragma unroll
  for (int ni = 0; ni < 4; ++ni) {
    int col = gx * 128 + wn + ni * 16 + tr;
    blov[ni] = eb[elo * HDIM + col];
    bhiv[ni] = eb[ehi * HDIM + col];
  }
#pragma unroll
  for (int mi = 0; mi < 4; ++mi)
#pragma unroll
    for (int r = 0; r < 4; ++r) {
      int lr = wm + mi * 16 + tq * 4 + r;
      if (row0 + lr < cntp) {
        int    tok = tok_s[lr];
        float2 pp  = pp_s[lr];
        float* orow = out + (size_t)tok * HDIM + gx * 128 + wn + tr;
#pragma unroll
        for (int ni = 0; ni < 4; ++ni)
          orow[ni * 16] = pp.x * (accL[mi][ni][r] + blov[ni]) +
                          pp.y * (accH[mi][ni][r] + bhiv[ni]);
      }
    }
}

extern "C" void kernel_launch(void* const* d_in, const int* in_sizes, int n_in,
                              void* d_out, int out_size, void* d_ws, size_t ws_size,
                              hipStream_t stream) {
  const float* x  = (const float*)d_in[0];
  const float* gw = (const float*)d_in[1];
  const float* gb = (const float*)d_in[2];
  const float* ew = (const float*)d_in[3];
  const float* eb = (const float*)d_in[4];
  float* out = (float*)d_out;
  char*  ws  = (char*)d_ws;

  __bf16* xb     = (__bf16*)(ws + XB_OFF);
  __bf16* wT     = (__bf16*)(ws + WT_OFF);
  int*    idx_p  = (int*)(ws + IDXP_OFF);
  float2* pp_p   = (float2*)(ws + PPP_OFF);
  int*    tt_pid = (int*)(ws + TPID_OFF);
  float2* tt_pp  = (float2*)(ws + TPP_OFF);
  int*    cnt_g  = (int*)(ws + CNT_OFF);
  int*    cur_g  = (int*)(ws + CUR_OFF);
  int*    base_g = (int*)(ws + BASE_OFF);
  int4*   tilt   = (int4*)(ws + TILT_OFF);
  int*    nt_g   = (int*)(ws + NT_OFF);
  float*  ent_g  = (float*)(ws + ENT_OFF);

  hipMemsetAsync(ws + CNT_OFF, 0, ZERO_LEN, stream);
  transpose_w<<<dim3(2048), 256, 0, stream>>>(ew, wT);
  gate_kernel<<<dim3(1024), 256, 0, stream>>>(x, gw, gb, xb, tt_pid, tt_pp,
                                              cnt_g, ent_g);
  scan_kernel<<<1, 64, 0, stream>>>(cnt_g, base_g, tilt, nt_g, ent_g,
                                    out + (size_t)NTOK * HDIM);
  scatter_kernel<<<dim3(64), 256, 0, stream>>>(tt_pid, tt_pp, base_g, cur_g,
                                               idx_p, pp_p);
  moe_gemm<<<dim3(8, 160), 256, 0, stream>>>(xb, wT, eb, idx_p, pp_p, tilt,
                                             nt_g, out);
}